// Round 1
// baseline (7729.911 us; speedup 1.0000x reference)
//
#include <hip/hip_runtime.h>
#include <hip/hip_bf16.h>
#include <float.h>
#include <math.h>

// Problem constants
#define NB 4
#define ND 512
#define NS 512
#define NH 8
#define NHD 64
#define NM 8192
#define NL 6
#define NFF 2048
#define NMLP 1024
#define NC 117

__device__ __forceinline__ float gelu_f(float x) {
    return 0.5f * x * (1.0f + erff(x * 0.70710678118654752440f));
}

// ---- mask 64^3 -> 8^3 trilinear (degenerates to 2x2x2 box avg at offsets 3,4) ----
__global__ void k_m8(const float* __restrict__ mask, float* __restrict__ m8) {
    int b = blockIdx.x, sp = threadIdx.x;
    int a = sp >> 6, bb = (sp >> 3) & 7, cc = sp & 7;
    const float* mb = mask + (size_t)b * 262144;
    int i0 = 8 * a + 3, j0 = 8 * bb + 3, k0 = 8 * cc + 3;
    float s = 0.f;
#pragma unroll
    for (int di = 0; di < 2; ++di)
#pragma unroll
        for (int dj = 0; dj < 2; ++dj)
#pragma unroll
            for (int dk = 0; dk < 2; ++dk)
                s += mb[(i0 + di) * 4096 + (j0 + dj) * 64 + (k0 + dk)];
    m8[b * NS + sp] = s * 0.125f;
}

// ---- tok[b][s][d] = x[b][d][s]*m8[b][s] + pe[d][s]  (tiled transpose) ----
__global__ void k_tok(const float* __restrict__ x, const float* __restrict__ pe,
                      const float* __restrict__ m8, float* __restrict__ tok) {
    __shared__ float t[32][33];
    int b = blockIdx.z;
    int sp0 = blockIdx.x * 32, d0 = blockIdx.y * 32;
    int tx = threadIdx.x, ty = threadIdx.y;
#pragma unroll
    for (int i = 0; i < 4; ++i) {
        int d = d0 + ty + i * 8;
        int sp = sp0 + tx;
        float v = x[((size_t)(b * ND + d)) * NS + sp] * m8[b * NS + sp] + pe[(size_t)d * NS + sp];
        t[ty + i * 8][tx] = v;
    }
    __syncthreads();
#pragma unroll
    for (int i = 0; i < 4; ++i) {
        int sp = sp0 + ty + i * 8;
        int d = d0 + tx;
        tok[((size_t)(b * NS) + sp) * ND + d] = t[tx][ty + i * 8];
    }
}

// ---- mem_k [B,M,64] -> memkT [B,64,M] ----
__global__ void k_memkT(const float* __restrict__ mk, float* __restrict__ mt) {
    __shared__ float t[32][33];
    int b = blockIdx.z;
    int m0 = blockIdx.x * 32, d0 = blockIdx.y * 32;
    int tx = threadIdx.x, ty = threadIdx.y;
    const float* src = mk + (size_t)b * NM * NHD;
    float* dst = mt + (size_t)b * NHD * NM;
#pragma unroll
    for (int i = 0; i < 4; ++i)
        t[ty + i * 8][tx] = src[(size_t)(m0 + ty + i * 8) * NHD + d0 + tx];
    __syncthreads();
#pragma unroll
    for (int i = 0; i < 4; ++i)
        dst[(size_t)(d0 + ty + i * 8) * NM + m0 + tx] = t[tx][ty + i * 8];
}

// ---- generic fp32 GEMM: C = epi(A[M,K] @ W[K,N] + bias [+ resid]) ----
// EPI: 0 = bias only, 1 = bias+gelu, 2 = bias+resid
template <int EPI>
__global__ __launch_bounds__(256) void k_gemm(
    const float* __restrict__ A, const float* __restrict__ W,
    const float* __restrict__ bias, const float* __restrict__ resid,
    float* __restrict__ C, int M, int N, int K) {
    __shared__ float As[16][68];
    __shared__ float Bs[16][68];
    int tid = threadIdx.x;
    int tx = tid & 15, ty = tid >> 4;
    int bn = blockIdx.x * 64, bm = blockIdx.y * 64;
    int lam = tid >> 2, lak = (tid & 3) * 4;
    int lbk = tid >> 4, lbn = (tid & 15) * 4;
    float acc[4][4] = {};
    const float* Ap = A + (size_t)(bm + lam) * K + lak;
    const float* Wp = W + (size_t)lbk * N + bn + lbn;
    for (int k0 = 0; k0 < K; k0 += 16) {
        float4 a4 = *(const float4*)(Ap + k0);
        float4 b4 = *(const float4*)(Wp + (size_t)k0 * N);
        As[lak + 0][lam] = a4.x;
        As[lak + 1][lam] = a4.y;
        As[lak + 2][lam] = a4.z;
        As[lak + 3][lam] = a4.w;
        *(float4*)&Bs[lbk][lbn] = b4;
        __syncthreads();
#pragma unroll
        for (int kk = 0; kk < 16; ++kk) {
            float4 av = *(const float4*)&As[kk][ty * 4];
            float4 bv = *(const float4*)&Bs[kk][tx * 4];
            acc[0][0] += av.x * bv.x; acc[0][1] += av.x * bv.y; acc[0][2] += av.x * bv.z; acc[0][3] += av.x * bv.w;
            acc[1][0] += av.y * bv.x; acc[1][1] += av.y * bv.y; acc[1][2] += av.y * bv.z; acc[1][3] += av.y * bv.w;
            acc[2][0] += av.z * bv.x; acc[2][1] += av.z * bv.y; acc[2][2] += av.z * bv.z; acc[2][3] += av.z * bv.w;
            acc[3][0] += av.w * bv.x; acc[3][1] += av.w * bv.y; acc[3][2] += av.w * bv.z; acc[3][3] += av.w * bv.w;
        }
        __syncthreads();
    }
    int col = bn + tx * 4;
    float4 bb4 = *(const float4*)&bias[col];
#pragma unroll
    for (int i = 0; i < 4; ++i) {
        int row = bm + ty * 4 + i;
        float4 o;
        o.x = acc[i][0] + bb4.x;
        o.y = acc[i][1] + bb4.y;
        o.z = acc[i][2] + bb4.z;
        o.w = acc[i][3] + bb4.w;
        if (EPI == 1) {
            o.x = gelu_f(o.x); o.y = gelu_f(o.y); o.z = gelu_f(o.z); o.w = gelu_f(o.w);
        } else if (EPI == 2) {
            float4 rr = *(const float4*)&resid[(size_t)row * N + col];
            o.x += rr.x; o.y += rr.y; o.z += rr.z; o.w += rr.w;
        }
        *(float4*)&C[(size_t)row * N + col] = o;
    }
}

// ---- fused flash attention: per (b,h,32-row q tile) ----
__global__ __launch_bounds__(256) void k_attn(const float* __restrict__ qkv,
                                              float* __restrict__ ao) {
    __shared__ float qs[32][65];
    __shared__ float ks[64][65];
    __shared__ float sc[32][68];
    __shared__ float pm[32][8];
    __shared__ float Mrow[32], Srow[32], Arow[32];
    int s0 = blockIdx.x * 32, h = blockIdx.y, b = blockIdx.z;
    int tid = threadIdx.x, tx = tid & 15, ty = tid >> 4;
    const float* base = qkv + (size_t)b * NS * 1536;
#pragma unroll
    for (int i = 0; i < 8; ++i) {
        int idx = tid + i * 256;
        int r = idx >> 6, d = idx & 63;
        qs[r][d] = base[(size_t)(s0 + r) * 1536 + h * 64 + d] * 0.125f;
    }
    if (tid < 32) { Mrow[tid] = -FLT_MAX; Srow[tid] = 0.f; }
    float accp[2][4] = {};
    int rg = tid >> 3, gg = tid & 7;
    for (int c = 0; c < 8; ++c) {
        __syncthreads();
#pragma unroll
        for (int i = 0; i < 16; ++i) {
            int idx = tid + i * 256;
            int r = idx >> 6, d = idx & 63;
            ks[r][d] = base[(size_t)(c * 64 + r) * 1536 + 512 + h * 64 + d];
        }
        __syncthreads();
        float a00 = 0, a01 = 0, a02 = 0, a03 = 0, a10 = 0, a11 = 0, a12 = 0, a13 = 0;
#pragma unroll 8
        for (int d = 0; d < 64; ++d) {
            float q0 = qs[ty][d], q1 = qs[ty + 16][d];
            float k0 = ks[tx][d], k1 = ks[tx + 16][d], k2 = ks[tx + 32][d], k3 = ks[tx + 48][d];
            a00 += q0 * k0; a01 += q0 * k1; a02 += q0 * k2; a03 += q0 * k3;
            a10 += q1 * k0; a11 += q1 * k1; a12 += q1 * k2; a13 += q1 * k3;
        }
        sc[ty][tx] = a00; sc[ty][tx + 16] = a01; sc[ty][tx + 32] = a02; sc[ty][tx + 48] = a03;
        sc[ty + 16][tx] = a10; sc[ty + 16][tx + 16] = a11; sc[ty + 16][tx + 32] = a12; sc[ty + 16][tx + 48] = a13;
        __syncthreads();
        // row stats (online softmax)
        float lm = -FLT_MAX;
#pragma unroll
        for (int j = 0; j < 8; ++j) lm = fmaxf(lm, sc[rg][gg * 8 + j]);
        pm[rg][gg] = lm;
        __syncthreads();
        if (gg == 0) {
            float nm = Mrow[rg];
#pragma unroll
            for (int j = 0; j < 8; ++j) nm = fmaxf(nm, pm[rg][j]);
            Arow[rg] = __expf(Mrow[rg] - nm);
            Mrow[rg] = nm;
        }
        __syncthreads();
        float mr = Mrow[rg];
        float ssp = 0.f;
#pragma unroll
        for (int j = 0; j < 8; ++j) {
            float e = __expf(sc[rg][gg * 8 + j] - mr);
            sc[rg][gg * 8 + j] = e;
            ssp += e;
        }
        pm[rg][gg] = ssp;
        __syncthreads();
        if (gg == 0) {
            float s2 = 0.f;
#pragma unroll
            for (int j = 0; j < 8; ++j) s2 += pm[rg][j];
            Srow[rg] = Srow[rg] * Arow[rg] + s2;
        }
        float al0 = Arow[ty], al1 = Arow[ty + 16];
#pragma unroll
        for (int j = 0; j < 4; ++j) { accp[0][j] *= al0; accp[1][j] *= al1; }
        __syncthreads();
        // load V chunk into ks
#pragma unroll
        for (int i = 0; i < 16; ++i) {
            int idx = tid + i * 256;
            int r = idx >> 6, d = idx & 63;
            ks[r][d] = base[(size_t)(c * 64 + r) * 1536 + 1024 + h * 64 + d];
        }
        __syncthreads();
#pragma unroll 8
        for (int kk = 0; kk < 64; ++kk) {
            float p0 = sc[ty][kk], p1 = sc[ty + 16][kk];
            float v0 = ks[kk][tx], v1 = ks[kk][tx + 16], v2 = ks[kk][tx + 32], v3 = ks[kk][tx + 48];
            accp[0][0] += p0 * v0; accp[0][1] += p0 * v1; accp[0][2] += p0 * v2; accp[0][3] += p0 * v3;
            accp[1][0] += p1 * v0; accp[1][1] += p1 * v1; accp[1][2] += p1 * v2; accp[1][3] += p1 * v3;
        }
    }
    __syncthreads();
    float inv0 = 1.0f / Srow[ty], inv1 = 1.0f / Srow[ty + 16];
    size_t o0 = ((size_t)(b * NS) + s0 + ty) * ND + h * 64;
    size_t o1 = ((size_t)(b * NS) + s0 + ty + 16) * ND + h * 64;
    ao[o0 + tx] = accp[0][0] * inv0;
    ao[o0 + tx + 16] = accp[0][1] * inv0;
    ao[o0 + tx + 32] = accp[0][2] * inv0;
    ao[o0 + tx + 48] = accp[0][3] * inv0;
    ao[o1 + tx] = accp[1][0] * inv1;
    ao[o1 + tx + 16] = accp[1][1] * inv1;
    ao[o1 + tx + 32] = accp[1][2] * inv1;
    ao[o1 + tx + 48] = accp[1][3] * inv1;
}

// ---- KNN memory: per (b,h,s): exact top-32 over 8192 sims, softmax, gather ----
__global__ __launch_bounds__(256) void k_knn(
    const float* __restrict__ qkv, const float* __restrict__ mkT,
    const float* __restrict__ mv, const float* __restrict__ gate,
    float* __restrict__ ao) {
    __shared__ float qs[64];
    __shared__ float sims[8192];
    __shared__ float rv[256];
    __shared__ int ri[256];
    __shared__ float topv[32];
    __shared__ int topi[32];
    __shared__ float wts[32];
    __shared__ float winv;
    int s = blockIdx.x, h = blockIdx.y, b = blockIdx.z;
    int tid = threadIdx.x;
    if (tid < 64)
        qs[tid] = qkv[((size_t)(b * NS) + s) * 1536 + h * 64 + tid] * 0.125f;
    __syncthreads();
    const float* kb = mkT + (size_t)b * NHD * NM;
#pragma unroll
    for (int c = 0; c < 8; ++c) {
        int m = c * 1024 + tid * 4;
        float ax = 0, ay = 0, az = 0, aw = 0;
        for (int d = 0; d < 64; ++d) {
            float q = qs[d];
            float4 kv = *(const float4*)&kb[(size_t)d * NM + m];
            ax += q * kv.x; ay += q * kv.y; az += q * kv.z; aw += q * kv.w;
        }
        float4 o; o.x = ax; o.y = ay; o.z = az; o.w = aw;
        *(float4*)&sims[m] = o;
    }
    __syncthreads();
    float lv = -FLT_MAX;
    int li = -1;
#pragma unroll
    for (int c = 0; c < 8; ++c)
#pragma unroll
        for (int j = 0; j < 4; ++j) {
            int m = c * 1024 + tid * 4 + j;
            float v = sims[m];
            if (v > lv) { lv = v; li = m; }
        }
    for (int it = 0; it < 32; ++it) {
        rv[tid] = lv; ri[tid] = li;
        __syncthreads();
        for (int off = 128; off >= 1; off >>= 1) {
            if (tid < off) {
                float ov = rv[tid + off];
                int oi = ri[tid + off];
                if (ov > rv[tid] || (ov == rv[tid] && oi < ri[tid])) { rv[tid] = ov; ri[tid] = oi; }
            }
            __syncthreads();
        }
        float wv = rv[0];
        int wi = ri[0];
        if (tid == 0) { topv[it] = wv; topi[it] = wi; }
        int owner = (wi & 1023) >> 2;
        if (tid == owner) {
            sims[wi] = -FLT_MAX;
            lv = -FLT_MAX; li = -1;
#pragma unroll
            for (int c = 0; c < 8; ++c)
#pragma unroll
                for (int j = 0; j < 4; ++j) {
                    int m = c * 1024 + tid * 4 + j;
                    float v = sims[m];
                    if (v > lv) { lv = v; li = m; }
                }
        }
        __syncthreads();
    }
    // softmax over the 32 (topv[0] is the max since selection is descending)
    if (tid < 32) wts[tid] = __expf(topv[tid] - topv[0]);
    __syncthreads();
    if (tid == 0) {
        float s2 = 0.f;
        for (int j = 0; j < 32; ++j) s2 += wts[j];
        winv = 1.0f / s2;
    }
    __syncthreads();
    if (tid < 64) {
        int d = tid;
        float acc = 0.f;
#pragma unroll 4
        for (int j = 0; j < 32; ++j)
            acc += wts[j] * mv[((size_t)b * NM + topi[j]) * NHD + d];
        acc *= winv;
        float g = 1.0f / (1.0f + __expf(-gate[h]));
        size_t oi = ((size_t)(b * NS) + s) * ND + h * 64 + d;
        ao[oi] = ao[oi] * (1.0f - g) + acc * g;
    }
}

// ---- LayerNorm over D=512 per row ----
__global__ __launch_bounds__(256) void k_ln(const float* __restrict__ X,
                                            const float* __restrict__ gam,
                                            const float* __restrict__ bet,
                                            float* __restrict__ Y) {
    __shared__ float red[4];
    __shared__ float sm, sv;
    int r = blockIdx.x, tid = threadIdx.x;
    const float* xr = X + (size_t)r * ND;
    float x0 = xr[tid], x1 = xr[tid + 256];
    float s = x0 + x1;
    for (int off = 32; off; off >>= 1) s += __shfl_down(s, off);
    if ((tid & 63) == 0) red[tid >> 6] = s;
    __syncthreads();
    if (tid == 0) sm = (red[0] + red[1] + red[2] + red[3]) * (1.0f / 512.0f);
    __syncthreads();
    float m = sm;
    float d0 = x0 - m, d1 = x1 - m;
    float vs = d0 * d0 + d1 * d1;
    for (int off = 32; off; off >>= 1) vs += __shfl_down(vs, off);
    if ((tid & 63) == 0) red[tid >> 6] = vs;
    __syncthreads();
    if (tid == 0) sv = rsqrtf((red[0] + red[1] + red[2] + red[3]) * (1.0f / 512.0f) + 1e-5f);
    __syncthreads();
    float rstd = sv;
    Y[(size_t)r * ND + tid] = d0 * rstd * gam[tid] + bet[tid];
    Y[(size_t)r * ND + tid + 256] = d1 * rstd * gam[tid + 256] + bet[tid + 256];
}

// ---- mean pool over S ----
__global__ void k_pool(const float* __restrict__ tok, float* __restrict__ pooled) {
    int b = blockIdx.x, d = threadIdx.x;
    float s = 0.f;
    for (int sp = 0; sp < NS; ++sp) s += tok[((size_t)(b * NS) + sp) * ND + d];
    pooled[b * ND + d] = s * (1.0f / 512.0f);
}

__global__ void k_fc1(const float* __restrict__ pooled, const float* __restrict__ w,
                      const float* __restrict__ bias, float* __restrict__ o1) {
    int id = blockIdx.x * 256 + threadIdx.x;  // 4096
    int b = id >> 10, j = id & 1023;
    float acc = bias[j];
    for (int d = 0; d < ND; ++d) acc += pooled[b * ND + d] * w[(size_t)d * NMLP + j];
    o1[id] = gelu_f(acc);
}

__global__ void k_fc2(const float* __restrict__ o1, const float* __restrict__ w,
                      const float* __restrict__ bias, float* __restrict__ out) {
    int id = blockIdx.x * 256 + threadIdx.x;
    if (id >= NB * NC) return;
    int b = id / NC, c = id % NC;
    float acc = bias[c];
    for (int k = 0; k < NMLP; ++k) acc += o1[b * NMLP + k] * w[(size_t)k * NC + c];
    out[id] = acc;
}

extern "C" void kernel_launch(void* const* d_in, const int* in_sizes, int n_in,
                              void* d_out, int out_size, void* d_ws, size_t ws_size,
                              hipStream_t stream) {
    const float* x    = (const float*)d_in[0];
    const float* mask = (const float*)d_in[1];
    const float* pe   = (const float*)d_in[2];
    const float* Wqkv = (const float*)d_in[3];
    const float* bqkv = (const float*)d_in[4];
    const float* Wo   = (const float*)d_in[5];
    const float* bo   = (const float*)d_in[6];
    const float* ln1g = (const float*)d_in[7];
    const float* ln1b = (const float*)d_in[8];
    const float* W1   = (const float*)d_in[9];
    const float* b1   = (const float*)d_in[10];
    const float* W2   = (const float*)d_in[11];
    const float* b2   = (const float*)d_in[12];
    const float* ln2g = (const float*)d_in[13];
    const float* ln2b = (const float*)d_in[14];
    const float* gate = (const float*)d_in[15];
    const float* memk = (const float*)d_in[16];
    const float* memv = (const float*)d_in[17];
    const float* fc1w = (const float*)d_in[18];
    const float* fc1b = (const float*)d_in[19];
    const float* fc2w = (const float*)d_in[20];
    const float* fc2b = (const float*)d_in[21];
    float* out = (float*)d_out;

    float* ws = (float*)d_ws;
    float* m8     = ws;                   // 2048
    float* mkT    = m8 + 2048;            // 4*64*8192 = 2097152
    float* tok    = mkT + 2097152;        // 2048*512 = 1048576
    float* qkv    = tok + 1048576;        // 2048*1536 = 3145728
    float* ao     = qkv + 3145728;        // 1048576
    float* ybuf   = ao + 1048576;         // 1048576
    float* ff1    = ybuf + 1048576;       // 2048*2048 = 4194304
    float* pooled = ff1 + 4194304;        // 2048
    float* o1     = pooled + 2048;        // 4096

    k_m8<<<NB, 512, 0, stream>>>(mask, m8);
    k_memkT<<<dim3(NM / 32, 2, NB), dim3(32, 8), 0, stream>>>(memk, mkT);
    k_tok<<<dim3(16, 16, NB), dim3(32, 8), 0, stream>>>(x, pe, m8, tok);

    for (int l = 0; l < NL; ++l) {
        k_gemm<0><<<dim3(24, 32), 256, 0, stream>>>(
            tok, Wqkv + (size_t)l * 512 * 1536, bqkv + l * 1536, nullptr, qkv, 2048, 1536, 512);
        k_attn<<<dim3(16, NH, NB), 256, 0, stream>>>(qkv, ao);
        if (l == 0)
            k_knn<<<dim3(NS, NH, NB), 256, 0, stream>>>(qkv, mkT, memv, gate, ao);
        k_gemm<2><<<dim3(8, 32), 256, 0, stream>>>(
            ao, Wo + (size_t)l * 512 * 512, bo + l * 512, tok, ybuf, 2048, 512, 512);
        k_ln<<<2048, 256, 0, stream>>>(ybuf, ln1g + l * 512, ln1b + l * 512, tok);
        k_gemm<1><<<dim3(32, 32), 256, 0, stream>>>(
            tok, W1 + (size_t)l * 512 * 2048, b1 + l * 2048, nullptr, ff1, 2048, 2048, 512);
        k_gemm<2><<<dim3(8, 32), 256, 0, stream>>>(
            ff1, W2 + (size_t)l * 2048 * 512, b2 + l * 512, tok, ybuf, 2048, 512, 2048);
        k_ln<<<2048, 256, 0, stream>>>(ybuf, ln2g + l * 512, ln2b + l * 512, tok);
    }

    k_pool<<<NB, 512, 0, stream>>>(tok, pooled);
    k_fc1<<<16, 256, 0, stream>>>(pooled, fc1w, fc1b, o1);
    k_fc2<<<2, 256, 0, stream>>>(o1, fc2w, fc2b, out);
}

// Round 2
// 3622.318 us; speedup vs baseline: 2.1340x; 2.1340x over previous
//
#include <hip/hip_runtime.h>
#include <hip/hip_bf16.h>
#include <float.h>
#include <math.h>

// Problem constants
#define NB 4
#define ND 512
#define NS 512
#define NH 8
#define NHD 64
#define NM 8192
#define NL 6
#define NFF 2048
#define NMLP 1024
#define NC 117

#define KCHUNK 256
#define NCH (NM / KCHUNK)
#define CAP 89

__device__ __forceinline__ float gelu_f(float x) {
    return 0.5f * x * (1.0f + erff(x * 0.70710678118654752440f));
}

// ---- mask 64^3 -> 8^3 trilinear (degenerates to 2x2x2 box avg at offsets 3,4) ----
__global__ void k_m8(const float* __restrict__ mask, float* __restrict__ m8) {
    int b = blockIdx.x, sp = threadIdx.x;
    int a = sp >> 6, bb = (sp >> 3) & 7, cc = sp & 7;
    const float* mb = mask + (size_t)b * 262144;
    int i0 = 8 * a + 3, j0 = 8 * bb + 3, k0 = 8 * cc + 3;
    float s = 0.f;
#pragma unroll
    for (int di = 0; di < 2; ++di)
#pragma unroll
        for (int dj = 0; dj < 2; ++dj)
#pragma unroll
            for (int dk = 0; dk < 2; ++dk)
                s += mb[(i0 + di) * 4096 + (j0 + dj) * 64 + (k0 + dk)];
    m8[b * NS + sp] = s * 0.125f;
}

// ---- tok[b][s][d] = x[b][d][s]*m8[b][s] + pe[d][s]  (tiled transpose) ----
__global__ void k_tok(const float* __restrict__ x, const float* __restrict__ pe,
                      const float* __restrict__ m8, float* __restrict__ tok) {
    __shared__ float t[32][33];
    int b = blockIdx.z;
    int sp0 = blockIdx.x * 32, d0 = blockIdx.y * 32;
    int tx = threadIdx.x, ty = threadIdx.y;
#pragma unroll
    for (int i = 0; i < 4; ++i) {
        int d = d0 + ty + i * 8;
        int sp = sp0 + tx;
        float v = x[((size_t)(b * ND + d)) * NS + sp] * m8[b * NS + sp] + pe[(size_t)d * NS + sp];
        t[ty + i * 8][tx] = v;
    }
    __syncthreads();
#pragma unroll
    for (int i = 0; i < 4; ++i) {
        int sp = sp0 + ty + i * 8;
        int d = d0 + tx;
        tok[((size_t)(b * NS) + sp) * ND + d] = t[tx][ty + i * 8];
    }
}

// ---- mem_k [B,M,64] -> memkT [B,64,M] ----
__global__ void k_memkT(const float* __restrict__ mk, float* __restrict__ mt) {
    __shared__ float t[32][33];
    int b = blockIdx.z;
    int m0 = blockIdx.x * 32, d0 = blockIdx.y * 32;
    int tx = threadIdx.x, ty = threadIdx.y;
    const float* src = mk + (size_t)b * NM * NHD;
    float* dst = mt + (size_t)b * NHD * NM;
#pragma unroll
    for (int i = 0; i < 4; ++i)
        t[ty + i * 8][tx] = src[(size_t)(m0 + ty + i * 8) * NHD + d0 + tx];
    __syncthreads();
#pragma unroll
    for (int i = 0; i < 4; ++i)
        dst[(size_t)(d0 + ty + i * 8) * NM + m0 + tx] = t[tx][ty + i * 8];
}

// ---- generic fp32 GEMM: C = epi(A[M,K] @ W[K,N] + bias [+ resid]) ----
// EPI: 0 = bias only, 1 = bias+gelu, 2 = bias+resid
template <int EPI>
__global__ __launch_bounds__(256) void k_gemm(
    const float* __restrict__ A, const float* __restrict__ W,
    const float* __restrict__ bias, const float* __restrict__ resid,
    float* __restrict__ C, int M, int N, int K) {
    __shared__ float As[16][68];
    __shared__ float Bs[16][68];
    int tid = threadIdx.x;
    int tx = tid & 15, ty = tid >> 4;
    int bn = blockIdx.x * 64, bm = blockIdx.y * 64;
    int lam = tid >> 2, lak = (tid & 3) * 4;
    int lbk = tid >> 4, lbn = (tid & 15) * 4;
    float acc[4][4] = {};
    const float* Ap = A + (size_t)(bm + lam) * K + lak;
    const float* Wp = W + (size_t)lbk * N + bn + lbn;
    for (int k0 = 0; k0 < K; k0 += 16) {
        float4 a4 = *(const float4*)(Ap + k0);
        float4 b4 = *(const float4*)(Wp + (size_t)k0 * N);
        As[lak + 0][lam] = a4.x;
        As[lak + 1][lam] = a4.y;
        As[lak + 2][lam] = a4.z;
        As[lak + 3][lam] = a4.w;
        *(float4*)&Bs[lbk][lbn] = b4;
        __syncthreads();
#pragma unroll
        for (int kk = 0; kk < 16; ++kk) {
            float4 av = *(const float4*)&As[kk][ty * 4];
            float4 bv = *(const float4*)&Bs[kk][tx * 4];
            acc[0][0] += av.x * bv.x; acc[0][1] += av.x * bv.y; acc[0][2] += av.x * bv.z; acc[0][3] += av.x * bv.w;
            acc[1][0] += av.y * bv.x; acc[1][1] += av.y * bv.y; acc[1][2] += av.y * bv.z; acc[1][3] += av.y * bv.w;
            acc[2][0] += av.z * bv.x; acc[2][1] += av.z * bv.y; acc[2][2] += av.z * bv.z; acc[2][3] += av.z * bv.w;
            acc[3][0] += av.w * bv.x; acc[3][1] += av.w * bv.y; acc[3][2] += av.w * bv.z; acc[3][3] += av.w * bv.w;
        }
        __syncthreads();
    }
    int col = bn + tx * 4;
    float4 bb4 = *(const float4*)&bias[col];
#pragma unroll
    for (int i = 0; i < 4; ++i) {
        int row = bm + ty * 4 + i;
        float4 o;
        o.x = acc[i][0] + bb4.x;
        o.y = acc[i][1] + bb4.y;
        o.z = acc[i][2] + bb4.z;
        o.w = acc[i][3] + bb4.w;
        if (EPI == 1) {
            o.x = gelu_f(o.x); o.y = gelu_f(o.y); o.z = gelu_f(o.z); o.w = gelu_f(o.w);
        } else if (EPI == 2) {
            float4 rr = *(const float4*)&resid[(size_t)row * N + col];
            o.x += rr.x; o.y += rr.y; o.z += rr.z; o.w += rr.w;
        }
        *(float4*)&C[(size_t)row * N + col] = o;
    }
}

// ---- fused flash attention: per (b,h,32-row q tile) ----
__global__ __launch_bounds__(256) void k_attn(const float* __restrict__ qkv,
                                              float* __restrict__ ao) {
    __shared__ float qs[32][65];
    __shared__ float ks[64][65];
    __shared__ float sc[32][68];
    __shared__ float pm[32][8];
    __shared__ float Mrow[32], Srow[32], Arow[32];
    int s0 = blockIdx.x * 32, h = blockIdx.y, b = blockIdx.z;
    int tid = threadIdx.x, tx = tid & 15, ty = tid >> 4;
    const float* base = qkv + (size_t)b * NS * 1536;
#pragma unroll
    for (int i = 0; i < 8; ++i) {
        int idx = tid + i * 256;
        int r = idx >> 6, d = idx & 63;
        qs[r][d] = base[(size_t)(s0 + r) * 1536 + h * 64 + d] * 0.125f;
    }
    if (tid < 32) { Mrow[tid] = -FLT_MAX; Srow[tid] = 0.f; }
    float accp[2][4] = {};
    int rg = tid >> 3, gg = tid & 7;
    for (int c = 0; c < 8; ++c) {
        __syncthreads();
#pragma unroll
        for (int i = 0; i < 16; ++i) {
            int idx = tid + i * 256;
            int r = idx >> 6, d = idx & 63;
            ks[r][d] = base[(size_t)(c * 64 + r) * 1536 + 512 + h * 64 + d];
        }
        __syncthreads();
        float a00 = 0, a01 = 0, a02 = 0, a03 = 0, a10 = 0, a11 = 0, a12 = 0, a13 = 0;
#pragma unroll 8
        for (int d = 0; d < 64; ++d) {
            float q0 = qs[ty][d], q1 = qs[ty + 16][d];
            float k0 = ks[tx][d], k1 = ks[tx + 16][d], k2 = ks[tx + 32][d], k3 = ks[tx + 48][d];
            a00 += q0 * k0; a01 += q0 * k1; a02 += q0 * k2; a03 += q0 * k3;
            a10 += q1 * k0; a11 += q1 * k1; a12 += q1 * k2; a13 += q1 * k3;
        }
        sc[ty][tx] = a00; sc[ty][tx + 16] = a01; sc[ty][tx + 32] = a02; sc[ty][tx + 48] = a03;
        sc[ty + 16][tx] = a10; sc[ty + 16][tx + 16] = a11; sc[ty + 16][tx + 32] = a12; sc[ty + 16][tx + 48] = a13;
        __syncthreads();
        // row stats (online softmax)
        float lm = -FLT_MAX;
#pragma unroll
        for (int j = 0; j < 8; ++j) lm = fmaxf(lm, sc[rg][gg * 8 + j]);
        pm[rg][gg] = lm;
        __syncthreads();
        if (gg == 0) {
            float nm = Mrow[rg];
#pragma unroll
            for (int j = 0; j < 8; ++j) nm = fmaxf(nm, pm[rg][j]);
            Arow[rg] = __expf(Mrow[rg] - nm);
            Mrow[rg] = nm;
        }
        __syncthreads();
        float mr = Mrow[rg];
        float ssp = 0.f;
#pragma unroll
        for (int j = 0; j < 8; ++j) {
            float e = __expf(sc[rg][gg * 8 + j] - mr);
            sc[rg][gg * 8 + j] = e;
            ssp += e;
        }
        pm[rg][gg] = ssp;
        __syncthreads();
        if (gg == 0) {
            float s2 = 0.f;
#pragma unroll
            for (int j = 0; j < 8; ++j) s2 += pm[rg][j];
            Srow[rg] = Srow[rg] * Arow[rg] + s2;
        }
        float al0 = Arow[ty], al1 = Arow[ty + 16];
#pragma unroll
        for (int j = 0; j < 4; ++j) { accp[0][j] *= al0; accp[1][j] *= al1; }
        __syncthreads();
        // load V chunk into ks
#pragma unroll
        for (int i = 0; i < 16; ++i) {
            int idx = tid + i * 256;
            int r = idx >> 6, d = idx & 63;
            ks[r][d] = base[(size_t)(c * 64 + r) * 1536 + 1024 + h * 64 + d];
        }
        __syncthreads();
#pragma unroll 8
        for (int kk = 0; kk < 64; ++kk) {
            float p0 = sc[ty][kk], p1 = sc[ty + 16][kk];
            float v0 = ks[kk][tx], v1 = ks[kk][tx + 16], v2 = ks[kk][tx + 32], v3 = ks[kk][tx + 48];
            accp[0][0] += p0 * v0; accp[0][1] += p0 * v1; accp[0][2] += p0 * v2; accp[0][3] += p0 * v3;
            accp[1][0] += p1 * v0; accp[1][1] += p1 * v1; accp[1][2] += p1 * v2; accp[1][3] += p1 * v3;
        }
    }
    __syncthreads();
    float inv0 = 1.0f / Srow[ty], inv1 = 1.0f / Srow[ty + 16];
    size_t o0 = ((size_t)(b * NS) + s0 + ty) * ND + h * 64;
    size_t o1 = ((size_t)(b * NS) + s0 + ty + 16) * ND + h * 64;
    ao[o0 + tx] = accp[0][0] * inv0;
    ao[o0 + tx + 16] = accp[0][1] * inv0;
    ao[o0 + tx + 32] = accp[0][2] * inv0;
    ao[o0 + tx + 48] = accp[0][3] * inv0;
    ao[o1 + tx] = accp[1][0] * inv1;
    ao[o1 + tx + 16] = accp[1][1] * inv1;
    ao[o1 + tx + 32] = accp[1][2] * inv1;
    ao[o1 + tx + 48] = accp[1][3] * inv1;
}

// ---- KNN memory v2: one block per (b, 8 s-values), 64 queries (8h x 8s) ----
// Streams mem_k in 256-col chunks; sims via 8x8 register microtiles; running
// exact top-32 in owner-lane registers with parallel threshold prefilter and
// overflow-retry for exactness on any data.
__global__ __launch_bounds__(256) void k_knn2(
    const float* __restrict__ qkv, const float* __restrict__ mkT,
    const float* __restrict__ mv, const float* __restrict__ gate,
    float* __restrict__ ao) {
    extern __shared__ float lds[];
    float* qs = lds;                                     // [64][64]  [d][q]
    float* ks = qs + 64 * 64;                            // [64][256] [d][m]
    float* cval = ks + 64 * 256;                         // [64][CAP]
    unsigned char* coff = (unsigned char*)(cval + 64 * CAP);  // [64][CAP]
    int* cnt = (int*)(coff + 64 * CAP);                  // [64]
    float* thrV = (float*)(cnt + 64);                    // [64]
    int* thrI = (int*)(thrV + 64);                       // [64]
    int* ovf = thrI + 64;                                // [1]
    // finale overlays on ks region:
    float* warr = ks;                                    // [64][33]
    int* iarr = (int*)(ks + 64 * 33);                    // [64][33]

    int b = blockIdx.y;
    int s0g = blockIdx.x * 8;
    int tid = threadIdx.x;
    int tx = tid & 31, ty = tid >> 5;

    // ---- prologue: load q tile (scaled), init state, stage chunk 0 ----
#pragma unroll
    for (int i = 0; i < 16; ++i) {
        int idx = i * 256 + tid;
        int q = idx & 63, d = idx >> 6;
        qs[d * 64 + q] =
            qkv[((size_t)(b * NS) + s0g + (q & 7)) * 1536 + (q >> 3) * 64 + d] * 0.125f;
    }
    if (tid < 64) { thrV[tid] = -FLT_MAX; thrI[tid] = 0x7FFFFFFF; cnt[tid] = 0; }
    if (tid == 0) *ovf = 0;

    {
        const float* src = mkT + (size_t)b * NHD * NM;
#pragma unroll
        for (int i = 0; i < 16; ++i) {
            int f4 = i * 256 + tid;
            int d = f4 >> 6, m4 = f4 & 63;
            float4 v = *(const float4*)(src + (size_t)d * NM + m4 * 4);
            *(float4*)&ks[d * 256 + m4 * 4] = v;
        }
    }

    float tv[32]; int ti[32];
#pragma unroll
    for (int j = 0; j < 32; ++j) { tv[j] = -FLT_MAX; ti[j] = 0x7FFFFFFF; }
    float wv = -FLT_MAX; int wi = 0x7FFFFFFF, wslot = 0;

    for (int c = 0; c < NCH; ++c) {
        __syncthreads();  // ks[c] ready; cnt zeroed; ovf=0; thr current

        // ---- compute 8q x 8m microtile over K=64 ----
        float acc[8][8];
#pragma unroll
        for (int qi = 0; qi < 8; ++qi)
#pragma unroll
            for (int mj = 0; mj < 8; ++mj) acc[qi][mj] = 0.f;
#pragma unroll 4
        for (int d = 0; d < 64; ++d) {
            float4 qa = *(const float4*)&qs[d * 64 + ty * 8];
            float4 qb = *(const float4*)&qs[d * 64 + ty * 8 + 4];
            float4 ka = *(const float4*)&ks[d * 256 + tx * 8];
            float4 kb = *(const float4*)&ks[d * 256 + tx * 8 + 4];
            float qv[8] = {qa.x, qa.y, qa.z, qa.w, qb.x, qb.y, qb.z, qb.w};
            float kv[8] = {ka.x, ka.y, ka.z, ka.w, kb.x, kb.y, kb.z, kb.w};
#pragma unroll
            for (int qi = 0; qi < 8; ++qi)
#pragma unroll
                for (int mj = 0; mj < 8; ++mj) acc[qi][mj] += qv[qi] * kv[mj];
        }

        // ---- phase A: prefilter accs vs running threshold, append candidates ----
#pragma unroll
        for (int qi = 0; qi < 8; ++qi) {
            int q = ty * 8 + qi;
            float tV = thrV[q]; int tI = thrI[q];
#pragma unroll
            for (int mj = 0; mj < 8; ++mj) {
                float v = acc[qi][mj];
                int off = tx * 8 + mj;
                int ci = c * KCHUNK + off;
                if (v > tV || (v == tV && ci < tI)) {
                    int pos = atomicAdd(&cnt[q], 1);
                    if (pos < CAP) {
                        cval[q * CAP + pos] = v;
                        coff[q * CAP + pos] = (unsigned char)off;
                    }
                }
            }
        }
        __syncthreads();  // candidates visible

        // stage next chunk (waves 2-3) concurrent with owner merge
        if (tid >= 128 && c + 1 < NCH) {
            const float* src = mkT + (size_t)b * NHD * NM + (size_t)(c + 1) * KCHUNK;
            int t = tid - 128;
#pragma unroll
            for (int i = 0; i < 32; ++i) {
                int f4 = i * 128 + t;
                int d = f4 >> 6, m4 = f4 & 63;
                float4 v = *(const float4*)(src + (size_t)d * NM + m4 * 4);
                *(float4*)&ks[d * 256 + m4 * 4] = v;
            }
        }

        // ---- phase B (+ retry loop for overflow exactness) ----
        for (int round = 0;; ++round) {
            if (tid < 64) {
                int q = tid;
                int n = cnt[q];
                bool of = n > CAP;
                if (n > CAP) n = CAP;
                for (int j = 0; j < n; ++j) {
                    float cv = cval[q * CAP + j];
                    int ci = c * KCHUNK + (int)coff[q * CAP + j];
                    if (cv > wv || (cv == wv && ci < wi)) {
                        bool dup = false;
                        if (round > 0) {
#pragma unroll
                            for (int k = 0; k < 32; ++k) dup = dup || (ti[k] == ci);
                        }
                        if (!dup) {
#pragma unroll
                            for (int k = 0; k < 32; ++k)
                                if (k == wslot) { tv[k] = cv; ti[k] = ci; }
                            wv = tv[0]; wi = ti[0]; wslot = 0;
#pragma unroll
                            for (int k = 1; k < 32; ++k) {
                                bool worse = (tv[k] < wv) || (tv[k] == wv && ti[k] > wi);
                                if (worse) { wv = tv[k]; wi = ti[k]; wslot = k; }
                            }
                        }
                    }
                }
                cnt[q] = 0;
                thrV[q] = wv; thrI[q] = wi;
                if (of) atomicOr(ovf, 1);
            }
            __syncthreads();
            if (*ovf == 0) break;
            __syncthreads();
            if (tid == 0) *ovf = 0;
            // re-scan accs vs tightened thresholds
#pragma unroll
            for (int qi = 0; qi < 8; ++qi) {
                int q = ty * 8 + qi;
                float tV = thrV[q]; int tI = thrI[q];
#pragma unroll
                for (int mj = 0; mj < 8; ++mj) {
                    float v = acc[qi][mj];
                    int off = tx * 8 + mj;
                    int ci = c * KCHUNK + off;
                    if (v > tV || (v == tV && ci < tI)) {
                        int pos = atomicAdd(&cnt[q], 1);
                        if (pos < CAP) {
                            cval[q * CAP + pos] = v;
                            coff[q * CAP + pos] = (unsigned char)off;
                        }
                    }
                }
            }
            __syncthreads();
        }
    }

    // ---- finale: softmax over top-32 (order-invariant), write weights ----
    __syncthreads();
    if (tid < 64) {
        int q = tid;
        float mx = tv[0];
#pragma unroll
        for (int j = 1; j < 32; ++j) mx = fmaxf(mx, tv[j]);
        float es[32]; float ssum = 0.f;
#pragma unroll
        for (int j = 0; j < 32; ++j) { es[j] = __expf(tv[j] - mx); ssum += es[j]; }
        float inv = 1.0f / ssum;
#pragma unroll
        for (int j = 0; j < 32; ++j) {
            warr[q * 33 + j] = es[j] * inv;
            iarr[q * 33 + j] = ti[j];
        }
    }
    __syncthreads();

    // ---- gather mem_v and blend into ao ----
    {
        int q = tid >> 2, dseg = (tid & 3) * 16;
        int h = q >> 3, si = q & 7;
        float a0x = 0, a0y = 0, a0z = 0, a0w = 0;
        float a1x = 0, a1y = 0, a1z = 0, a1w = 0;
        float a2x = 0, a2y = 0, a2z = 0, a2w = 0;
        float a3x = 0, a3y = 0, a3z = 0, a3w = 0;
        const float* vb = mv + (size_t)b * NM * NHD;
        for (int j = 0; j < 32; ++j) {
            float w = warr[q * 33 + j];
            int idx = iarr[q * 33 + j];
            const float* row = vb + (size_t)idx * NHD + dseg;
            float4 v0 = *(const float4*)(row);
            float4 v1 = *(const float4*)(row + 4);
            float4 v2 = *(const float4*)(row + 8);
            float4 v3 = *(const float4*)(row + 12);
            a0x += w * v0.x; a0y += w * v0.y; a0z += w * v0.z; a0w += w * v0.w;
            a1x += w * v1.x; a1y += w * v1.y; a1z += w * v1.z; a1w += w * v1.w;
            a2x += w * v2.x; a2y += w * v2.y; a2z += w * v2.z; a2w += w * v2.w;
            a3x += w * v3.x; a3y += w * v3.y; a3z += w * v3.z; a3w += w * v3.w;
        }
        float g = 1.0f / (1.0f + __expf(-gate[h]));
        float omg = 1.0f - g;
        float* aop = ao + ((size_t)(b * NS) + s0g + si) * ND + h * 64 + dseg;
        float r[16] = {a0x, a0y, a0z, a0w, a1x, a1y, a1z, a1w,
                       a2x, a2y, a2z, a2w, a3x, a3y, a3z, a3w};
#pragma unroll
        for (int k = 0; k < 16; ++k) aop[k] = aop[k] * omg + r[k] * g;
    }
}

// ---- LayerNorm over D=512 per row ----
__global__ __launch_bounds__(256) void k_ln(const float* __restrict__ X,
                                            const float* __restrict__ gam,
                                            const float* __restrict__ bet,
                                            float* __restrict__ Y) {
    __shared__ float red[4];
    __shared__ float sm, sv;
    int r = blockIdx.x, tid = threadIdx.x;
    const float* xr = X + (size_t)r * ND;
    float x0 = xr[tid], x1 = xr[tid + 256];
    float s = x0 + x1;
    for (int off = 32; off; off >>= 1) s += __shfl_down(s, off);
    if ((tid & 63) == 0) red[tid >> 6] = s;
    __syncthreads();
    if (tid == 0) sm = (red[0] + red[1] + red[2] + red[3]) * (1.0f / 512.0f);
    __syncthreads();
    float m = sm;
    float d0 = x0 - m, d1 = x1 - m;
    float vs = d0 * d0 + d1 * d1;
    for (int off = 32; off; off >>= 1) vs += __shfl_down(vs, off);
    if ((tid & 63) == 0) red[tid >> 6] = vs;
    __syncthreads();
    if (tid == 0) sv = rsqrtf((red[0] + red[1] + red[2] + red[3]) * (1.0f / 512.0f) + 1e-5f);
    __syncthreads();
    float rstd = sv;
    Y[(size_t)r * ND + tid] = d0 * rstd * gam[tid] + bet[tid];
    Y[(size_t)r * ND + tid + 256] = d1 * rstd * gam[tid + 256] + bet[tid + 256];
}

// ---- mean pool over S ----
__global__ void k_pool(const float* __restrict__ tok, float* __restrict__ pooled) {
    int b = blockIdx.x, d = threadIdx.x;
    float s = 0.f;
    for (int sp = 0; sp < NS; ++sp) s += tok[((size_t)(b * NS) + sp) * ND + d];
    pooled[b * ND + d] = s * (1.0f / 512.0f);
}

__global__ void k_fc1(const float* __restrict__ pooled, const float* __restrict__ w,
                      const float* __restrict__ bias, float* __restrict__ o1) {
    int id = blockIdx.x * 256 + threadIdx.x;  // 4096
    int b = id >> 10, j = id & 1023;
    float acc = bias[j];
    for (int d = 0; d < ND; ++d) acc += pooled[b * ND + d] * w[(size_t)d * NMLP + j];
    o1[id] = gelu_f(acc);
}

__global__ void k_fc2(const float* __restrict__ o1, const float* __restrict__ w,
                      const float* __restrict__ bias, float* __restrict__ out) {
    int id = blockIdx.x * 256 + threadIdx.x;
    if (id >= NB * NC) return;
    int b = id / NC, c = id % NC;
    float acc = bias[c];
    for (int k = 0; k < NMLP; ++k) acc += o1[b * NMLP + k] * w[(size_t)k * NC + c];
    out[id] = acc;
}

extern "C" void kernel_launch(void* const* d_in, const int* in_sizes, int n_in,
                              void* d_out, int out_size, void* d_ws, size_t ws_size,
                              hipStream_t stream) {
    const float* x    = (const float*)d_in[0];
    const float* mask = (const float*)d_in[1];
    const float* pe   = (const float*)d_in[2];
    const float* Wqkv = (const float*)d_in[3];
    const float* bqkv = (const float*)d_in[4];
    const float* Wo   = (const float*)d_in[5];
    const float* bo   = (const float*)d_in[6];
    const float* ln1g = (const float*)d_in[7];
    const float* ln1b = (const float*)d_in[8];
    const float* W1   = (const float*)d_in[9];
    const float* b1   = (const float*)d_in[10];
    const float* W2   = (const float*)d_in[11];
    const float* b2   = (const float*)d_in[12];
    const float* ln2g = (const float*)d_in[13];
    const float* ln2b = (const float*)d_in[14];
    const float* gate = (const float*)d_in[15];
    const float* memk = (const float*)d_in[16];
    const float* memv = (const float*)d_in[17];
    const float* fc1w = (const float*)d_in[18];
    const float* fc1b = (const float*)d_in[19];
    const float* fc2w = (const float*)d_in[20];
    const float* fc2b = (const float*)d_in[21];
    float* out = (float*)d_out;

    float* ws = (float*)d_ws;
    float* m8     = ws;                   // 2048
    float* mkT    = m8 + 2048;            // 4*64*8192 = 2097152
    float* tok    = mkT + 2097152;        // 2048*512 = 1048576
    float* qkv    = tok + 1048576;        // 2048*1536 = 3145728
    float* ao     = qkv + 3145728;        // 1048576
    float* ybuf   = ao + 1048576;         // 1048576
    float* ff1    = ybuf + 1048576;       // 2048*2048 = 4194304
    float* pooled = ff1 + 4194304;        // 2048
    float* o1     = pooled + 2048;        // 4096

    k_m8<<<NB, 512, 0, stream>>>(mask, m8);
    k_memkT<<<dim3(NM / 32, 2, NB), dim3(32, 8), 0, stream>>>(memk, mkT);
    k_tok<<<dim3(16, 16, NB), dim3(32, 8), 0, stream>>>(x, pe, m8, tok);

    // dynamic LDS size for k_knn2
    size_t knnLds = (size_t)(64 * 64 + 64 * 256 + 64 * CAP) * 4  // qs, ks, cval
                    + 64 * CAP                                    // coff (u8)
                    + 64 * 4 * 3 + 16;                            // cnt, thrV, thrI, ovf

    for (int l = 0; l < NL; ++l) {
        k_gemm<0><<<dim3(24, 32), 256, 0, stream>>>(
            tok, Wqkv + (size_t)l * 512 * 1536, bqkv + l * 1536, nullptr, qkv, 2048, 1536, 512);
        k_attn<<<dim3(16, NH, NB), 256, 0, stream>>>(qkv, ao);
        if (l == 0)
            k_knn2<<<dim3(64, NB), 256, knnLds, stream>>>(qkv, mkT, memv, gate, ao);
        k_gemm<2><<<dim3(8, 32), 256, 0, stream>>>(
            ao, Wo + (size_t)l * 512 * 512, bo + l * 512, tok, ybuf, 2048, 512, 512);
        k_ln<<<2048, 256, 0, stream>>>(ybuf, ln1g + l * 512, ln1b + l * 512, tok);
        k_gemm<1><<<dim3(32, 32), 256, 0, stream>>>(
            tok, W1 + (size_t)l * 512 * 2048, b1 + l * 2048, nullptr, ff1, 2048, 2048, 512);
        k_gemm<2><<<dim3(8, 32), 256, 0, stream>>>(
            ff1, W2 + (size_t)l * 2048 * 512, b2 + l * 512, tok, ybuf, 2048, 512, 2048);
        k_ln<<<2048, 256, 0, stream>>>(ybuf, ln2g + l * 512, ln2b + l * 512, tok);
    }

    k_pool<<<NB, 512, 0, stream>>>(tok, pooled);
    k_fc1<<<16, 256, 0, stream>>>(pooled, fc1w, fc1b, o1);
    k_fc2<<<2, 256, 0, stream>>>(o1, fc2w, fc2b, out);
}

// Round 3
// 2575.484 us; speedup vs baseline: 3.0013x; 1.4065x over previous
//
#include <hip/hip_runtime.h>
#include <hip/hip_bf16.h>
#include <float.h>
#include <math.h>

// Problem constants
#define NB 4
#define ND 512
#define NS 512
#define NH 8
#define NHD 64
#define NM 8192
#define NL 6
#define NFF 2048
#define NMLP 1024
#define NC 117

// knn3 params
#define KC3 128
#define NCH3 (NM / KC3)
#define CAP3 64

typedef __attribute__((ext_vector_type(8))) short s16x8;
typedef __attribute__((ext_vector_type(4))) float f32x4;

__device__ __forceinline__ float gelu_f(float x) {
    return 0.5f * x * (1.0f + erff(x * 0.70710678118654752440f));
}

__device__ __forceinline__ ushort f2bf_rne(float x) {
    uint u = __float_as_uint(x);
    uint r = u + 0x7FFFu + ((u >> 16) & 1u);
    return (ushort)(r >> 16);
}
__device__ __forceinline__ float bf2f(ushort h) { return __uint_as_float(((uint)h) << 16); }
__device__ __forceinline__ void split1(float x, ushort& h, ushort& l) {
    h = f2bf_rne(x);
    float r = x - bf2f(h);
    l = f2bf_rne(r);
}
__device__ __forceinline__ void split8(const float* v, s16x8& hv, s16x8& lv) {
#pragma unroll
    for (int j = 0; j < 8; ++j) {
        ushort h, l;
        split1(v[j], h, l);
        hv[j] = (short)h;
        lv[j] = (short)l;
    }
}

// ---- mask 64^3 -> 8^3 trilinear (degenerates to 2x2x2 box avg at offsets 3,4) ----
__global__ void k_m8(const float* __restrict__ mask, float* __restrict__ m8) {
    int b = blockIdx.x, sp = threadIdx.x;
    int a = sp >> 6, bb = (sp >> 3) & 7, cc = sp & 7;
    const float* mb = mask + (size_t)b * 262144;
    int i0 = 8 * a + 3, j0 = 8 * bb + 3, k0 = 8 * cc + 3;
    float s = 0.f;
#pragma unroll
    for (int di = 0; di < 2; ++di)
#pragma unroll
        for (int dj = 0; dj < 2; ++dj)
#pragma unroll
            for (int dk = 0; dk < 2; ++dk)
                s += mb[(i0 + di) * 4096 + (j0 + dj) * 64 + (k0 + dk)];
    m8[b * NS + sp] = s * 0.125f;
}

// ---- tok[b][s][d] = x[b][d][s]*m8[b][s] + pe[d][s]  (tiled transpose) ----
__global__ void k_tok(const float* __restrict__ x, const float* __restrict__ pe,
                      const float* __restrict__ m8, float* __restrict__ tok) {
    __shared__ float t[32][33];
    int b = blockIdx.z;
    int sp0 = blockIdx.x * 32, d0 = blockIdx.y * 32;
    int tx = threadIdx.x, ty = threadIdx.y;
#pragma unroll
    for (int i = 0; i < 4; ++i) {
        int d = d0 + ty + i * 8;
        int sp = sp0 + tx;
        float v = x[((size_t)(b * ND + d)) * NS + sp] * m8[b * NS + sp] + pe[(size_t)d * NS + sp];
        t[ty + i * 8][tx] = v;
    }
    __syncthreads();
#pragma unroll
    for (int i = 0; i < 4; ++i) {
        int sp = sp0 + ty + i * 8;
        int d = d0 + tx;
        tok[((size_t)(b * NS) + sp) * ND + d] = t[tx][ty + i * 8];
    }
}

// ---- mem_k fp32 -> bf16 hi/lo (same [b][m][d] layout) ----
__global__ void k_mksplit(const float* __restrict__ mk, ushort* __restrict__ mh,
                          ushort* __restrict__ ml) {
    size_t i4 = ((size_t)blockIdx.x * 256 + threadIdx.x) * 4;
    float4 v = *(const float4*)&mk[i4];
    float vv[4] = {v.x, v.y, v.z, v.w};
    ushort h[4], l[4];
#pragma unroll
    for (int j = 0; j < 4; ++j) split1(vv[j], h[j], l[j]);
    *(ushort4*)&mh[i4] = make_ushort4(h[0], h[1], h[2], h[3]);
    *(ushort4*)&ml[i4] = make_ushort4(l[0], l[1], l[2], l[3]);
}

// ---- exact fp32 GEMM (kept for layer-0 qkv: knn selection needs fp32-exact q) ----
template <int EPI>
__global__ __launch_bounds__(256) void k_gemm(
    const float* __restrict__ A, const float* __restrict__ W,
    const float* __restrict__ bias, const float* __restrict__ resid,
    float* __restrict__ C, int M, int N, int K) {
    __shared__ float As[16][68];
    __shared__ float Bs[16][68];
    int tid = threadIdx.x;
    int tx = tid & 15, ty = tid >> 4;
    int bn = blockIdx.x * 64, bm = blockIdx.y * 64;
    int lam = tid >> 2, lak = (tid & 3) * 4;
    int lbk = tid >> 4, lbn = (tid & 15) * 4;
    float acc[4][4] = {};
    const float* Ap = A + (size_t)(bm + lam) * K + lak;
    const float* Wp = W + (size_t)lbk * N + bn + lbn;
    for (int k0 = 0; k0 < K; k0 += 16) {
        float4 a4 = *(const float4*)(Ap + k0);
        float4 b4 = *(const float4*)(Wp + (size_t)k0 * N);
        As[lak + 0][lam] = a4.x;
        As[lak + 1][lam] = a4.y;
        As[lak + 2][lam] = a4.z;
        As[lak + 3][lam] = a4.w;
        *(float4*)&Bs[lbk][lbn] = b4;
        __syncthreads();
#pragma unroll
        for (int kk = 0; kk < 16; ++kk) {
            float4 av = *(const float4*)&As[kk][ty * 4];
            float4 bv = *(const float4*)&Bs[kk][tx * 4];
            acc[0][0] += av.x * bv.x; acc[0][1] += av.x * bv.y; acc[0][2] += av.x * bv.z; acc[0][3] += av.x * bv.w;
            acc[1][0] += av.y * bv.x; acc[1][1] += av.y * bv.y; acc[1][2] += av.y * bv.z; acc[1][3] += av.y * bv.w;
            acc[2][0] += av.z * bv.x; acc[2][1] += av.z * bv.y; acc[2][2] += av.z * bv.z; acc[2][3] += av.z * bv.w;
            acc[3][0] += av.w * bv.x; acc[3][1] += av.w * bv.y; acc[3][2] += av.w * bv.z; acc[3][3] += av.w * bv.w;
        }
        __syncthreads();
    }
    int col = bn + tx * 4;
    float4 bb4 = *(const float4*)&bias[col];
#pragma unroll
    for (int i = 0; i < 4; ++i) {
        int row = bm + ty * 4 + i;
        float4 o;
        o.x = acc[i][0] + bb4.x;
        o.y = acc[i][1] + bb4.y;
        o.z = acc[i][2] + bb4.z;
        o.w = acc[i][3] + bb4.w;
        if (EPI == 1) {
            o.x = gelu_f(o.x); o.y = gelu_f(o.y); o.z = gelu_f(o.z); o.w = gelu_f(o.w);
        } else if (EPI == 2) {
            float4 rr = *(const float4*)&resid[(size_t)row * N + col];
            o.x += rr.x; o.y += rr.y; o.z += rr.z; o.w += rr.w;
        }
        *(float4*)&C[(size_t)row * N + col] = o;
    }
}

// ---- split-bf16 MFMA GEMM: C = epi(A @ W + bias [+resid]), 3-pass hi/lo ----
// A [M][K] fp32 row-major; W [K][N] fp32 row-major (transposed+split during staging)
template <int BM, int BN, int EPI>
__global__ __launch_bounds__(256) void k_gmm(
    const float* __restrict__ A, const float* __restrict__ W,
    const float* __restrict__ bias, const float* __restrict__ resid,
    float* __restrict__ C, int M, int N, int K) {
    constexpr int PAD = 40;  // bf16 row stride: 80B (16B-aligned frags, ~2-way banks)
    constexpr int FM = BM / 32, FN = BN / 32;
    __shared__ __align__(16) ushort Ah[BM * PAD];
    __shared__ __align__(16) ushort Al[BM * PAD];
    __shared__ __align__(16) ushort Bh[BN * PAD];
    __shared__ __align__(16) ushort Bl[BN * PAD];
    int tid = threadIdx.x, lane = tid & 63, wvi = tid >> 6;
    int wr = wvi >> 1, wc = wvi & 1;
    int bn = blockIdx.x * BN, bm = blockIdx.y * BM;

    constexpr int FPTA = BM / 8;      // floats of A per thread per k-step
    constexpr int TPRA = 32 / FPTA;   // threads per A-row
    int arow = tid / TPRA;
    int akoff = (tid % TPRA) * FPTA;
    const float* Ap = A + (size_t)(bm + arow) * K + akoff;

    constexpr int FPTB = BN / 8;      // floats of W per thread (along n)
    int bkrow = tid >> 3;
    int bnoff = (tid & 7) * FPTB;
    const float* Wp = W + (size_t)bkrow * N + bn + bnoff;

    float abuf[FPTA], bbuf[FPTB];
#pragma unroll
    for (int j = 0; j < FPTA; j += 4) *(float4*)&abuf[j] = *(const float4*)(Ap + j);
#pragma unroll
    for (int j = 0; j < FPTB; j += 4) *(float4*)&bbuf[j] = *(const float4*)(Wp + j);

    f32x4 acc[FM][FN] = {};

    for (int k0 = 0; k0 < K; k0 += 32) {
        // convert staged regs -> LDS
#pragma unroll
        for (int g = 0; g < FPTA / 8; ++g) {
            s16x8 hv, lv;
            split8(&abuf[g * 8], hv, lv);
            *(s16x8*)&Ah[arow * PAD + akoff + g * 8] = hv;
            *(s16x8*)&Al[arow * PAD + akoff + g * 8] = lv;
        }
#pragma unroll
        for (int j = 0; j < FPTB; ++j) {
            ushort h, l;
            split1(bbuf[j], h, l);
            Bh[(bnoff + j) * PAD + bkrow] = h;
            Bl[(bnoff + j) * PAD + bkrow] = l;
        }
        __syncthreads();
        if (k0 + 32 < K) {
#pragma unroll
            for (int j = 0; j < FPTA; j += 4)
                *(float4*)&abuf[j] = *(const float4*)(Ap + k0 + 32 + j);
#pragma unroll
            for (int j = 0; j < FPTB; j += 4)
                *(float4*)&bbuf[j] = *(const float4*)(Wp + (size_t)(k0 + 32) * N + j);
        }
        s16x8 fah[FM], fal[FM], fbh[FN], fbl[FN];
        int kb = (lane >> 4) * 8;
#pragma unroll
        for (int fm = 0; fm < FM; ++fm) {
            int row = wr * (BM / 2) + fm * 16 + (lane & 15);
            fah[fm] = *(const s16x8*)&Ah[row * PAD + kb];
            fal[fm] = *(const s16x8*)&Al[row * PAD + kb];
        }
#pragma unroll
        for (int fn = 0; fn < FN; ++fn) {
            int row = wc * (BN / 2) + fn * 16 + (lane & 15);
            fbh[fn] = *(const s16x8*)&Bh[row * PAD + kb];
            fbl[fn] = *(const s16x8*)&Bl[row * PAD + kb];
        }
#pragma unroll
        for (int fm = 0; fm < FM; ++fm)
#pragma unroll
            for (int fn = 0; fn < FN; ++fn) {
                acc[fm][fn] = __builtin_amdgcn_mfma_f32_16x16x32_bf16(fah[fm], fbh[fn], acc[fm][fn], 0, 0, 0);
                acc[fm][fn] = __builtin_amdgcn_mfma_f32_16x16x32_bf16(fah[fm], fbl[fn], acc[fm][fn], 0, 0, 0);
                acc[fm][fn] = __builtin_amdgcn_mfma_f32_16x16x32_bf16(fal[fm], fbh[fn], acc[fm][fn], 0, 0, 0);
            }
        __syncthreads();
    }
#pragma unroll
    for (int fm = 0; fm < FM; ++fm) {
#pragma unroll
        for (int fn = 0; fn < FN; ++fn) {
            int n = bn + wc * (BN / 2) + fn * 16 + (lane & 15);
            float bb = bias[n];
#pragma unroll
            for (int r = 0; r < 4; ++r) {
                int m = bm + wr * (BM / 2) + fm * 16 + (lane >> 4) * 4 + r;
                float o = acc[fm][fn][r] + bb;
                if (EPI == 1) o = gelu_f(o);
                else if (EPI == 2) o += resid[(size_t)m * N + n];
                C[(size_t)m * N + n] = o;
            }
        }
    }
}

// ---- fused flash attention: per (b,h,32-row q tile) ----
__global__ __launch_bounds__(256) void k_attn(const float* __restrict__ qkv,
                                              float* __restrict__ ao) {
    __shared__ float qs[32][65];
    __shared__ float ks[64][65];
    __shared__ float sc[32][68];
    __shared__ float pm[32][8];
    __shared__ float Mrow[32], Srow[32], Arow[32];
    int s0 = blockIdx.x * 32, h = blockIdx.y, b = blockIdx.z;
    int tid = threadIdx.x, tx = tid & 15, ty = tid >> 4;
    const float* base = qkv + (size_t)b * NS * 1536;
#pragma unroll
    for (int i = 0; i < 8; ++i) {
        int idx = tid + i * 256;
        int r = idx >> 6, d = idx & 63;
        qs[r][d] = base[(size_t)(s0 + r) * 1536 + h * 64 + d] * 0.125f;
    }
    if (tid < 32) { Mrow[tid] = -FLT_MAX; Srow[tid] = 0.f; }
    float accp[2][4] = {};
    int rg = tid >> 3, gg = tid & 7;
    for (int c = 0; c < 8; ++c) {
        __syncthreads();
#pragma unroll
        for (int i = 0; i < 16; ++i) {
            int idx = tid + i * 256;
            int r = idx >> 6, d = idx & 63;
            ks[r][d] = base[(size_t)(c * 64 + r) * 1536 + 512 + h * 64 + d];
        }
        __syncthreads();
        float a00 = 0, a01 = 0, a02 = 0, a03 = 0, a10 = 0, a11 = 0, a12 = 0, a13 = 0;
#pragma unroll 8
        for (int d = 0; d < 64; ++d) {
            float q0 = qs[ty][d], q1 = qs[ty + 16][d];
            float k0 = ks[tx][d], k1 = ks[tx + 16][d], k2 = ks[tx + 32][d], k3 = ks[tx + 48][d];
            a00 += q0 * k0; a01 += q0 * k1; a02 += q0 * k2; a03 += q0 * k3;
            a10 += q1 * k0; a11 += q1 * k1; a12 += q1 * k2; a13 += q1 * k3;
        }
        sc[ty][tx] = a00; sc[ty][tx + 16] = a01; sc[ty][tx + 32] = a02; sc[ty][tx + 48] = a03;
        sc[ty + 16][tx] = a10; sc[ty + 16][tx + 16] = a11; sc[ty + 16][tx + 32] = a12; sc[ty + 16][tx + 48] = a13;
        __syncthreads();
        float lm = -FLT_MAX;
#pragma unroll
        for (int j = 0; j < 8; ++j) lm = fmaxf(lm, sc[rg][gg * 8 + j]);
        pm[rg][gg] = lm;
        __syncthreads();
        if (gg == 0) {
            float nm = Mrow[rg];
#pragma unroll
            for (int j = 0; j < 8; ++j) nm = fmaxf(nm, pm[rg][j]);
            Arow[rg] = __expf(Mrow[rg] - nm);
            Mrow[rg] = nm;
        }
        __syncthreads();
        float mr = Mrow[rg];
        float ssp = 0.f;
#pragma unroll
        for (int j = 0; j < 8; ++j) {
            float e = __expf(sc[rg][gg * 8 + j] - mr);
            sc[rg][gg * 8 + j] = e;
            ssp += e;
        }
        pm[rg][gg] = ssp;
        __syncthreads();
        if (gg == 0) {
            float s2 = 0.f;
#pragma unroll
            for (int j = 0; j < 8; ++j) s2 += pm[rg][j];
            Srow[rg] = Srow[rg] * Arow[rg] + s2;
        }
        float al0 = Arow[ty], al1 = Arow[ty + 16];
#pragma unroll
        for (int j = 0; j < 4; ++j) { accp[0][j] *= al0; accp[1][j] *= al1; }
        __syncthreads();
#pragma unroll
        for (int i = 0; i < 16; ++i) {
            int idx = tid + i * 256;
            int r = idx >> 6, d = idx & 63;
            ks[r][d] = base[(size_t)(c * 64 + r) * 1536 + 1024 + h * 64 + d];
        }
        __syncthreads();
#pragma unroll 8
        for (int kk = 0; kk < 64; ++kk) {
            float p0 = sc[ty][kk], p1 = sc[ty + 16][kk];
            float v0 = ks[kk][tx], v1 = ks[kk][tx + 16], v2 = ks[kk][tx + 32], v3 = ks[kk][tx + 48];
            accp[0][0] += p0 * v0; accp[0][1] += p0 * v1; accp[0][2] += p0 * v2; accp[0][3] += p0 * v3;
            accp[1][0] += p1 * v0; accp[1][1] += p1 * v1; accp[1][2] += p1 * v2; accp[1][3] += p1 * v3;
        }
    }
    __syncthreads();
    float inv0 = 1.0f / Srow[ty], inv1 = 1.0f / Srow[ty + 16];
    size_t o0 = ((size_t)(b * NS) + s0 + ty) * ND + h * 64;
    size_t o1 = ((size_t)(b * NS) + s0 + ty + 16) * ND + h * 64;
    ao[o0 + tx] = accp[0][0] * inv0;
    ao[o0 + tx + 16] = accp[0][1] * inv0;
    ao[o0 + tx + 32] = accp[0][2] * inv0;
    ao[o0 + tx + 48] = accp[0][3] * inv0;
    ao[o1 + tx] = accp[1][0] * inv1;
    ao[o1 + tx + 16] = accp[1][1] * inv1;
    ao[o1 + tx + 32] = accp[1][2] * inv1;
    ao[o1 + tx + 48] = accp[1][3] * inv1;
}

__device__ __forceinline__ void stage_krow(const ushort* __restrict__ src,
                                           ushort* __restrict__ dstbase, int row) {
#pragma unroll
    for (int i = 0; i < 8; ++i) {
        uint4 w = *(const uint4*)(src + i * 8);
        *(uint4*)((char*)dstbase + row * 128 + ((i * 16) ^ ((row & 7) << 4))) = w;
    }
}

// ---- KNN memory v3: MFMA sims + register top-32 with threshold prefilter ----
// grid (128, NB): block = (b, 4 s-values) -> 32 queries (8h x 4s), 256 thr.
__global__ __launch_bounds__(256) void k_knn3(
    const float* __restrict__ qkv, const ushort* __restrict__ mkh,
    const ushort* __restrict__ mkl, const float* __restrict__ mv,
    const float* __restrict__ gate, float* __restrict__ ao) {
    __shared__ __align__(16) ushort qh[32 * 64], ql[32 * 64];   // 4KB each, swizzled
    __shared__ __align__(16) ushort kh[KC3 * 64], kl[KC3 * 64]; // 16KB each, swizzled
    __shared__ float cval[32 * CAP3];
    __shared__ unsigned char coff[32 * CAP3];
    __shared__ int cnt[32];
    __shared__ float thrV[32];
    __shared__ int thrI[32];
    __shared__ int ovf;
    float* warr = (float*)kh;  // finale overlay [32][33]
    int* iarr = (int*)kl;      // finale overlay [32][33]

    int b = blockIdx.y, s0 = blockIdx.x * 4;
    int tid = threadIdx.x, lane = tid & 63, wvi = tid >> 6;

    // stage q (scaled, split, swizzled): q = h*4+si
    {
        int q = tid >> 3, dbase = (tid & 7) * 8;
        const float* src = &qkv[((size_t)(b * NS) + s0 + (q & 3)) * 1536 + (q >> 2) * 64 + dbase];
        float v[8];
#pragma unroll
        for (int j = 0; j < 8; ++j) v[j] = src[j] * 0.125f;
        s16x8 hv, lv;
        split8(v, hv, lv);
        int by = q * 128 + ((dbase * 2) ^ ((q & 7) << 4));
        *(s16x8*)((char*)qh + by) = hv;
        *(s16x8*)((char*)ql + by) = lv;
    }
    if (tid < 32) { thrV[tid] = -FLT_MAX; thrI[tid] = 0x7FFFFFFF; cnt[tid] = 0; }
    if (tid == 0) ovf = 0;
    // stage chunk 0: threads 0-127 hi rows, 128-255 lo rows
    {
        int t = tid & 127;
        const ushort* srcb = (tid < 128 ? mkh : mkl) + ((size_t)b * NM + t) * 64;
        stage_krow(srcb, (tid < 128 ? kh : kl), t);
    }

    float tv[32];
    int ti[32];
#pragma unroll
    for (int j = 0; j < 32; ++j) { tv[j] = -FLT_MAX; ti[j] = 0x7FFFFFFF; }
    float wv = -FLT_MAX;
    int wi = 0x7FFFFFFF, wslot = 0;

    for (int c = 0; c < NCH3; ++c) {
        __syncthreads();  // ks ready, cnt=0, thr current

        // ---- sims via 3-pass split-bf16 MFMA: 2 q-frags x 2 m-frags x 2 ksteps ----
        f32x4 acc[2][2] = {};
#pragma unroll
        for (int kstep = 0; kstep < 2; ++kstep) {
            int kb2 = (kstep * 32 + (lane >> 4) * 8) * 2;  // byte offset pre-swizzle
            s16x8 fqh[2], fql[2], fkh[2], fkl[2];
#pragma unroll
            for (int fq = 0; fq < 2; ++fq) {
                int row = fq * 16 + (lane & 15);
                int by = row * 128 + (kb2 ^ ((row & 7) << 4));
                fqh[fq] = *(const s16x8*)((const char*)qh + by);
                fql[fq] = *(const s16x8*)((const char*)ql + by);
            }
#pragma unroll
            for (int fm = 0; fm < 2; ++fm) {
                int row = wvi * 32 + fm * 16 + (lane & 15);
                int by = row * 128 + (kb2 ^ ((row & 7) << 4));
                fkh[fm] = *(const s16x8*)((const char*)kh + by);
                fkl[fm] = *(const s16x8*)((const char*)kl + by);
            }
#pragma unroll
            for (int fq = 0; fq < 2; ++fq)
#pragma unroll
                for (int fm = 0; fm < 2; ++fm) {
                    acc[fq][fm] = __builtin_amdgcn_mfma_f32_16x16x32_bf16(fqh[fq], fkh[fm], acc[fq][fm], 0, 0, 0);
                    acc[fq][fm] = __builtin_amdgcn_mfma_f32_16x16x32_bf16(fqh[fq], fkl[fm], acc[fq][fm], 0, 0, 0);
                    acc[fq][fm] = __builtin_amdgcn_mfma_f32_16x16x32_bf16(fql[fq], fkh[fm], acc[fq][fm], 0, 0, 0);
                }
        }

        // ---- phase A: prefilter C-frag values vs running thresholds ----
#pragma unroll
        for (int fq = 0; fq < 2; ++fq)
#pragma unroll
            for (int fm = 0; fm < 2; ++fm)
#pragma unroll
                for (int r = 0; r < 4; ++r) {
                    float v = acc[fq][fm][r];
                    int q = fq * 16 + (lane >> 4) * 4 + r;
                    int mloc = wvi * 32 + fm * 16 + (lane & 15);
                    int ci = c * KC3 + mloc;
                    float tV = thrV[q];
                    int tI = thrI[q];
                    if (v > tV || (v == tV && ci < tI)) {
                        int pos = atomicAdd(&cnt[q], 1);
                        if (pos < CAP3) {
                            cval[q * CAP3 + pos] = v;
                            coff[q * CAP3 + pos] = (unsigned char)mloc;
                        }
                    }
                }
        __syncthreads();  // candidates visible; all LDS k reads done

        // stage next chunk (waves 2-3) concurrent with owner merge
        if (tid >= 128 && c + 1 < NCH3) {
            int t = tid - 128;
            size_t mo = ((size_t)b * NM + (size_t)(c + 1) * KC3 + t) * 64;
            stage_krow(mkh + mo, kh, t);
            stage_krow(mkl + mo, kl, t);
        }

        // ---- phase B merge (+ overflow retry for exactness) ----
        for (int round = 0;; ++round) {
            if (tid < 32) {
                int q = tid;
                int n = cnt[q];
                bool of = n > CAP3;
                if (n > CAP3) n = CAP3;
                for (int j = 0; j < n; ++j) {
                    float cv = cval[q * CAP3 + j];
                    int ci = c * KC3 + (int)coff[q * CAP3 + j];
                    if (cv > wv || (cv == wv && ci < wi)) {
                        bool dup = false;
                        if (round > 0) {
#pragma unroll
                            for (int k = 0; k < 32; ++k) dup = dup || (ti[k] == ci);
                        }
                        if (!dup) {
#pragma unroll
                            for (int k = 0; k < 32; ++k)
                                if (k == wslot) { tv[k] = cv; ti[k] = ci; }
                            wv = tv[0]; wi = ti[0]; wslot = 0;
#pragma unroll
                            for (int k = 1; k < 32; ++k) {
                                bool worse = (tv[k] < wv) || (tv[k] == wv && ti[k] > wi);
                                if (worse) { wv = tv[k]; wi = ti[k]; wslot = k; }
                            }
                        }
                    }
                }
                cnt[q] = 0;
                thrV[q] = wv;
                thrI[q] = wi;
                if (of) atomicOr(&ovf, 1);
            }
            __syncthreads();
            if (ovf == 0) break;
            __syncthreads();
            if (tid == 0) ovf = 0;
#pragma unroll
            for (int fq = 0; fq < 2; ++fq)
#pragma unroll
                for (int fm = 0; fm < 2; ++fm)
#pragma unroll
                    for (int r = 0; r < 4; ++r) {
                        float v = acc[fq][fm][r];
                        int q = fq * 16 + (lane >> 4) * 4 + r;
                        int mloc = wvi * 32 + fm * 16 + (lane & 15);
                        int ci = c * KC3 + mloc;
                        float tV = thrV[q];
                        int tI = thrI[q];
                        if (v > tV || (v == tV && ci < tI)) {
                            int pos = atomicAdd(&cnt[q], 1);
                            if (pos < CAP3) {
                                cval[q * CAP3 + pos] = v;
                                coff[q * CAP3 + pos] = (unsigned char)mloc;
                            }
                        }
                    }
            __syncthreads();
        }
    }

    // ---- finale: softmax over top-32 (order-invariant) ----
    __syncthreads();
    if (tid < 32) {
        int q = tid;
        float mx = tv[0];
#pragma unroll
        for (int j = 1; j < 32; ++j) mx = fmaxf(mx, tv[j]);
        float ssum = 0.f;
        float es[32];
#pragma unroll
        for (int j = 0; j < 32; ++j) { es[j] = __expf(tv[j] - mx); ssum += es[j]; }
        float inv = 1.0f / ssum;
#pragma unroll
        for (int j = 0; j < 32; ++j) {
            warr[q * 33 + j] = es[j] * inv;
            iarr[q * 33 + j] = ti[j];
        }
    }
    __syncthreads();

    // ---- gather mem_v and blend into ao ----
    {
        int q = tid >> 3, dseg = (tid & 7) * 8;
        int h = q >> 2, si = q & 3;
        float r0x = 0, r0y = 0, r0z = 0, r0w = 0, r1x = 0, r1y = 0, r1z = 0, r1w = 0;
        const float* vb = mv + (size_t)b * NM * NHD;
        for (int j = 0; j < 32; ++j) {
            float w = warr[q * 33 + j];
            int idx = iarr[q * 33 + j];
            const float* row = vb + (size_t)idx * NHD + dseg;
            float4 v0 = *(const float4*)(row);
            float4 v1 = *(const float4*)(row + 4);
            r0x += w * v0.x; r0y += w * v0.y; r0z += w * v0.z; r0w += w * v0.w;
            r1x += w * v1.x; r1y += w * v1.y; r1z += w * v1.z; r1w += w * v1.w;
        }
        float g = 1.0f / (1.0f + __expf(-gate[h]));
        float omg = 1.0f - g;
        float* aop = ao + ((size_t)(b * NS) + s0 + si) * ND + h * 64 + dseg;
        float rr[8] = {r0x, r0y, r0z, r0w, r1x, r1y, r1z, r1w};
#pragma unroll
        for (int k = 0; k < 8; ++k) aop[k] = aop[k] * omg + rr[k] * g;
    }
}

// ---- LayerNorm over D=512 per row ----
__global__ __launch_bounds__(256) void k_ln(const float* __restrict__ X,
                                            const float* __restrict__ gam,
                                            const float* __restrict__ bet,
                                            float* __restrict__ Y) {
    __shared__ float red[4];
    __shared__ float sm, sv;
    int r = blockIdx.x, tid = threadIdx.x;
    const float* xr = X + (size_t)r * ND;
    float x0 = xr[tid], x1 = xr[tid + 256];
    float s = x0 + x1;
    for (int off = 32; off; off >>= 1) s += __shfl_down(s, off);
    if ((tid & 63) == 0) red[tid >> 6] = s;
    __syncthreads();
    if (tid == 0) sm = (red[0] + red[1] + red[2] + red[3]) * (1.0f / 512.0f);
    __syncthreads();
    float m = sm;
    float d0 = x0 - m, d1 = x1 - m;
    float vs = d0 * d0 + d1 * d1;
    for (int off = 32; off; off >>= 1) vs += __shfl_down(vs, off);
    if ((tid & 63) == 0) red[tid >> 6] = vs;
    __syncthreads();
    if (tid == 0) sv = rsqrtf((red[0] + red[1] + red[2] + red[3]) * (1.0f / 512.0f) + 1e-5f);
    __syncthreads();
    float rstd = sv;
    Y[(size_t)r * ND + tid] = d0 * rstd * gam[tid] + bet[tid];
    Y[(size_t)r * ND + tid + 256] = d1 * rstd * gam[tid + 256] + bet[tid + 256];
}

// ---- mean pool over S ----
__global__ void k_pool(const float* __restrict__ tok, float* __restrict__ pooled) {
    int b = blockIdx.x, d = threadIdx.x;
    float s = 0.f;
    for (int sp = 0; sp < NS; ++sp) s += tok[((size_t)(b * NS) + sp) * ND + d];
    pooled[b * ND + d] = s * (1.0f / 512.0f);
}

__global__ void k_fc1(const float* __restrict__ pooled, const float* __restrict__ w,
                      const float* __restrict__ bias, float* __restrict__ o1) {
    int id = blockIdx.x * 256 + threadIdx.x;  // 4096
    int b = id >> 10, j = id & 1023;
    float acc = bias[j];
    for (int d = 0; d < ND; ++d) acc += pooled[b * ND + d] * w[(size_t)d * NMLP + j];
    o1[id] = gelu_f(acc);
}

__global__ void k_fc2(const float* __restrict__ o1, const float* __restrict__ w,
                      const float* __restrict__ bias, float* __restrict__ out) {
    int id = blockIdx.x * 256 + threadIdx.x;
    if (id >= NB * NC) return;
    int b = id / NC, c = id % NC;
    float acc = bias[c];
    for (int k = 0; k < NMLP; ++k) acc += o1[b * NMLP + k] * w[(size_t)k * NC + c];
    out[id] = acc;
}

extern "C" void kernel_launch(void* const* d_in, const int* in_sizes, int n_in,
                              void* d_out, int out_size, void* d_ws, size_t ws_size,
                              hipStream_t stream) {
    const float* x    = (const float*)d_in[0];
    const float* mask = (const float*)d_in[1];
    const float* pe   = (const float*)d_in[2];
    const float* Wqkv = (const float*)d_in[3];
    const float* bqkv = (const float*)d_in[4];
    const float* Wo   = (const float*)d_in[5];
    const float* bo   = (const float*)d_in[6];
    const float* ln1g = (const float*)d_in[7];
    const float* ln1b = (const float*)d_in[8];
    const float* W1   = (const float*)d_in[9];
    const float* b1   = (const float*)d_in[10];
    const float* W2   = (const float*)d_in[11];
    const float* b2   = (const float*)d_in[12];
    const float* ln2g = (const float*)d_in[13];
    const float* ln2b = (const float*)d_in[14];
    const float* gate = (const float*)d_in[15];
    const float* memk = (const float*)d_in[16];
    const float* memv = (const float*)d_in[17];
    const float* fc1w = (const float*)d_in[18];
    const float* fc1b = (const float*)d_in[19];
    const float* fc2w = (const float*)d_in[20];
    const float* fc2b = (const float*)d_in[21];
    float* out = (float*)d_out;

    float* ws = (float*)d_ws;
    float* m8     = ws;                       // 2048
    ushort* mkh   = (ushort*)(m8 + 2048);     // 2097152 ushort (= 1048576 floats)
    ushort* mkl   = mkh + 2097152;            // 2097152 ushort
    float* tok    = (float*)(mkl + 2097152);  // 1048576
    float* qkv    = tok + 1048576;            // 3145728
    float* ao     = qkv + 3145728;            // 1048576
    float* ybuf   = ao + 1048576;             // 1048576
    float* ff1    = ybuf + 1048576;           // 4194304
    float* pooled = ff1 + 4194304;            // 2048
    float* o1     = pooled + 2048;            // 4096

    k_m8<<<NB, 512, 0, stream>>>(mask, m8);
    k_mksplit<<<2048, 256, 0, stream>>>(memk, mkh, mkl);
    k_tok<<<dim3(16, 16, NB), dim3(32, 8), 0, stream>>>(x, pe, m8, tok);

    for (int l = 0; l < NL; ++l) {
        if (l == 0)
            k_gemm<0><<<dim3(24, 32), 256, 0, stream>>>(
                tok, Wqkv, bqkv, nullptr, qkv, 2048, 1536, 512);
        else
            k_gmm<128, 128, 0><<<dim3(12, 16), 256, 0, stream>>>(
                tok, Wqkv + (size_t)l * 512 * 1536, bqkv + l * 1536, nullptr, qkv, 2048, 1536, 512);
        k_attn<<<dim3(16, NH, NB), 256, 0, stream>>>(qkv, ao);
        if (l == 0)
            k_knn3<<<dim3(128, NB), 256, 0, stream>>>(qkv, mkh, mkl, memv, gate, ao);
        k_gmm<64, 64, 2><<<dim3(8, 32), 256, 0, stream>>>(
            ao, Wo + (size_t)l * 512 * 512, bo + l * 512, tok, ybuf, 2048, 512, 512);
        k_ln<<<2048, 256, 0, stream>>>(ybuf, ln1g + l * 512, ln1b + l * 512, tok);
        k_gmm<128, 128, 1><<<dim3(16, 16), 256, 0, stream>>>(
            tok, W1 + (size_t)l * 512 * 2048, b1 + l * 2048, nullptr, ff1, 2048, 2048, 512);
        k_gmm<64, 64, 2><<<dim3(8, 32), 256, 0, stream>>>(
            ff1, W2 + (size_t)l * 2048 * 512, b2 + l * 512, tok, ybuf, 2048, 512, 2048);
        k_ln<<<2048, 256, 0, stream>>>(ybuf, ln2g + l * 512, ln2b + l * 512, tok);
    }

    k_pool<<<NB, 512, 0, stream>>>(tok, pooled);
    k_fc1<<<16, 256, 0, stream>>>(pooled, fc1w, fc1b, o1);
    k_fc2<<<2, 256, 0, stream>>>(o1, fc2w, fc2b, out);
}